// Round 10
// baseline (39.461 us; speedup 1.0000x reference)
//
#include <hip/hip_runtime.h>
#include <math.h>

// SoftHd via bf16 MFMA. 2 pairs per block, counted-vmcnt K-quarter pipeline,
// DPP quad folds + shfl merge-reductions (permlane32_swap removed: semantics
// unverified on HW and the round-9 failure points at it).
// out[b1,b2] = sum_{j<sz2} min_{i<sz1} dist[i,j] + sum_{i<sz1} min_{j<sz2} dist[i,j]
// dist via gemm identity on bf16-rounded inputs; sqrt monotone -> mins on
// squared distances, sqrt after reduction; masking folded into +INF operands.
// Quarter-blocked global bf16 layout (pre-kernel):
//   panel byte off(r,c16) = (c16>>2)*8192 + (r>>3)*512 + (c16&3)*128 + (r&7)*16

typedef __attribute__((ext_vector_type(8))) short short8;
typedef __attribute__((ext_vector_type(4))) float f32x4;
typedef unsigned int u32;
typedef unsigned short ushort_t;

static __device__ __forceinline__ ushort_t f32_to_bf16_rne(float f) {
    u32 b = __float_as_uint(f);
    b += 0x7FFFu + ((b >> 16) & 1u);
    return (ushort_t)(b >> 16);
}

// DPP quad_perm folds (VALU pipe, not LDS): xor1 = [1,0,3,2] = 0xB1,
// xor2 = [2,3,0,1] = 0x4E. Semantics are standard DPP, verified mapping.
#define DPPX1(x) __int_as_float(__builtin_amdgcn_update_dpp( \
    0, __float_as_int(x), 0xB1, 0xF, 0xF, true))
#define DPPX2(x) __int_as_float(__builtin_amdgcn_update_dpp( \
    0, __float_as_int(x), 0x4E, 0xF, 0xF, true))

// ---------------------------------------------------------------------------
// Pre-kernel: f32 -> bf16 into quarter-blocked layout + per-row squared norms
// (fp32 of the ROUNDED values).
// ---------------------------------------------------------------------------
__global__ __launch_bounds__(256) void softhd_pre(
    const float* __restrict__ v1, const float* __restrict__ v2,
    ushort_t* __restrict__ v1b, ushort_t* __restrict__ v2b,
    float* __restrict__ x2g, float* __restrict__ y2g)
{
    int flat = blockIdx.x * 256 + threadIdx.x;
    int c = flat & 15;
    int r = (flat >> 4) & 127;
    int b = (flat >> 11) & 63;
    int t = flat >> 17;

    const float* src = (t ? v2 : v1) + ((size_t)((b << 7) + r) << 7) + c * 8;
    char* dstp = (char*)((t ? v2b : v1b) + ((size_t)b << 14));

    float4 q0 = *(const float4*)(src);
    float4 q1 = *(const float4*)(src + 4);

    ushort_t h[8];
    h[0] = f32_to_bf16_rne(q0.x); h[1] = f32_to_bf16_rne(q0.y);
    h[2] = f32_to_bf16_rne(q0.z); h[3] = f32_to_bf16_rne(q0.w);
    h[4] = f32_to_bf16_rne(q1.x); h[5] = f32_to_bf16_rne(q1.y);
    h[6] = f32_to_bf16_rne(q1.z); h[7] = f32_to_bf16_rne(q1.w);

    float p = 0.f;
#pragma unroll
    for (int k = 0; k < 8; ++k) {
        float fv = __uint_as_float((u32)h[k] << 16);
        p += fv * fv;
    }

    uint4 w;
    w.x = (u32)h[0] | ((u32)h[1] << 16);
    w.y = (u32)h[2] | ((u32)h[3] << 16);
    w.z = (u32)h[4] | ((u32)h[5] << 16);
    w.w = (u32)h[6] | ((u32)h[7] << 16);

    int off = ((c >> 2) << 13) + ((r >> 3) << 9) + ((c & 3) << 7) + ((r & 7) << 4);
    *(uint4*)(dstp + off) = w;

    p += __shfl_xor(p, 1);
    p += __shfl_xor(p, 2);
    p += __shfl_xor(p, 4);
    p += __shfl_xor(p, 8);
    if (c == 0) (t ? y2g : x2g)[(b << 7) + r] = p;
}

// ---------------------------------------------------------------------------
// Main kernel: 2048 blocks = 64 b1 x 32 b2-pairs. 4 waves, 2x2 quadrant split.
// ---------------------------------------------------------------------------
__global__ __launch_bounds__(256, 4) void softhd_mfma(
    const ushort_t* __restrict__ v1b, const ushort_t* __restrict__ v2b,
    const float* __restrict__ x2g, const float* __restrict__ y2g,
    const int* __restrict__ sz1, const int* __restrict__ sz2,
    float* __restrict__ out)
{
    __shared__ __align__(16) ushort_t sb[2][2][4096];  // [buf][panel][8 KB]
    __shared__ float sx2[128], sy2[2][128];
    __shared__ u32 sbm1[128], sbm2[128];
    __shared__ float swsum[4];

    const int tid = threadIdx.x;
    const int lane = tid & 63;
    const int wid = tid >> 6;
    // XCD-bijective swizzle (2048 % 8 == 0).
    const int bid = ((blockIdx.x & 7) << 8) | (blockIdx.x >> 3);
    const int b1 = bid >> 5;
    const int b2base = (bid & 31) << 1;

    const char* gp0 = (const char*)(v1b + ((size_t)b1 << 14));
    const char* gB0 = (const char*)(v2b + ((size_t)(b2base + 0) << 14));
    const char* gB1 = (const char*)(v2b + ((size_t)(b2base + 1) << 14));

    const int n1 = min(max(sz1[b1], 0), 128);
    int n2v[2];
    n2v[0] = min(max(sz2[b2base + 0], 0), 128);
    n2v[1] = min(max(sz2[b2base + 1], 0), 128);

    // Norm loads + LDS init first, fully retired before any STAGE issues.
    if (tid < 128) {
        sx2[tid] = x2g[(b1 << 7) + tid];
        sbm1[tid] = 0x7F800000u;            // +inf bits
        sbm2[tid] = 0x7F800000u;
    } else {
        sy2[0][tid - 128] = y2g[((b2base + 0) << 7) + (tid - 128)];
        sy2[1][tid - 128] = y2g[((b2base + 1) << 7) + (tid - 128)];
    }
    asm volatile("" ::: "memory");          // pin order: init before staging

#define STAGE(d, gB, q)                                                      \
    {                                                                        \
        _Pragma("unroll")                                                    \
        for (int e = 0; e < 2; ++e) {                                        \
            int m16 = ((e << 8) + tid) << 4;                                 \
            __builtin_amdgcn_global_load_lds(                                \
                (const __attribute__((address_space(1))) u32*)(gp0 + ((q) << 13) + m16), \
                (__attribute__((address_space(3))) u32*)((char*)&sb[d][0][0] + m16),     \
                16, 0, 0);                                                   \
            __builtin_amdgcn_global_load_lds(                                \
                (const __attribute__((address_space(1))) u32*)((gB) + ((q) << 13) + m16),\
                (__attribute__((address_space(3))) u32*)((char*)&sb[d][1][0] + m16),     \
                16, 0, 0);                                                   \
        }                                                                    \
    }
#define WAITV4()  asm volatile("s_waitcnt vmcnt(4)" ::: "memory")
#define WAITV0()  asm volatile("s_waitcnt vmcnt(0)" ::: "memory")
#define BAR()     asm volatile("s_barrier" ::: "memory")
#define LGKMBAR() do { asm volatile("s_waitcnt lgkmcnt(0)" ::: "memory");    \
                       asm volatile("s_barrier" ::: "memory"); } while (0)

    STAGE(0, gB0, 0);
    STAGE(1, gB0, 1);

    const int qr = wid >> 1, qc = wid & 1;
    const int ibase = qr << 6, jbase = qc << 6;
    const int rf = lane & 15, kg = lane >> 4;
    const bool h0 = lane & 1, h1 = lane & 2, h2 = lane & 4, h3 = lane & 8;
    const bool h4 = lane & 16, h5 = lane & 32;

    // frag elem offsets within an 8 KB quarter: (row>>3)*256 + kg*64 + (row&7)*8
    int aoff[4], boff[4];
#pragma unroll
    for (int f = 0; f < 4; ++f) {
        int ra = ibase + (f << 4) + rf;
        int rb = jbase + (f << 4) + rf;
        aoff[f] = ((ra >> 3) << 8) + (kg << 6) + ((ra & 7) << 3);
        boff[f] = ((rb >> 3) << 8) + (kg << 6) + ((rb & 7) << 3);
    }

    f32x4 acc[4][4];
#pragma unroll
    for (int fi = 0; fi < 4; ++fi)
#pragma unroll
        for (int fj = 0; fj < 4; ++fj)
            acc[fi][fj] = (f32x4){0.f, 0.f, 0.f, 0.f};

#define COMPUTE(d)                                                           \
    {                                                                        \
        short8 a[4], b[4];                                                   \
        _Pragma("unroll")                                                    \
        for (int f = 0; f < 4; ++f) {                                        \
            a[f] = *(const short8*)(&sb[d][0][0] + aoff[f]);                 \
            b[f] = *(const short8*)(&sb[d][1][0] + boff[f]);                 \
        }                                                                    \
        _Pragma("unroll")                                                    \
        for (int fi = 0; fi < 4; ++fi)                                       \
            _Pragma("unroll")                                                \
            for (int fj = 0; fj < 4; ++fj)                                   \
                acc[fi][fj] = __builtin_amdgcn_mfma_f32_16x16x32_bf16(       \
                    a[fi], b[fj], acc[fi][fj], 0, 0, 0);                     \
    }

    const float INF = __builtin_inff();

    // Epilogue for pair p. mini side: fold lane bits 0,1 (DPP, VALU pipe)
    // inside the fi loop; bits 2,3 via shfl. minj side: fold bits 5 then 4
    // via shfl (rounds-5..8-verified ladder). fj = bit5 | (bit4<<1).
#define EPILOGUE(p)                                                          \
    {                                                                        \
        const int nn2 = n2v[p];                                              \
        float yje[4];                                                        \
        _Pragma("unroll")                                                    \
        for (int fj = 0; fj < 4; ++fj) {                                     \
            int j = jbase + (fj << 4) + rf;                                  \
            yje[fj] = (j < nn2) ? sy2[p][j] : INF;                           \
        }                                                                    \
        float minj[4] = {INF, INF, INF, INF};                                \
        float mini4[4];                                                      \
        _Pragma("unroll")                                                    \
        for (int fi = 0; fi < 4; ++fi) {                                     \
            const int i0 = ibase + (fi << 4) + (kg << 2);                    \
            float4 xs = *(const float4*)&sx2[i0];                            \
            float xie[4];                                                    \
            xie[0] = (i0 + 0 < n1) ? xs.x : INF;                             \
            xie[1] = (i0 + 1 < n1) ? xs.y : INF;                             \
            xie[2] = (i0 + 2 < n1) ? xs.z : INF;                             \
            xie[3] = (i0 + 3 < n1) ? xs.w : INF;                             \
            float u[4][4];                                                   \
            _Pragma("unroll")                                                \
            for (int fj = 0; fj < 4; ++fj) {                                 \
                _Pragma("unroll")                                            \
                for (int q = 0; q < 4; ++q)                                  \
                    u[fj][q] = fmaf(acc[fi][fj][q], -2.f, xie[q] + yje[fj]); \
                minj[fj] = fminf(fminf(minj[fj], u[fj][0]), u[fj][1]);       \
                minj[fj] = fminf(fminf(minj[fj], u[fj][2]), u[fj][3]);       \
            }                                                                \
            float mq0 = fminf(fminf(u[0][0], u[1][0]), fminf(u[2][0], u[3][0])); \
            float mq1 = fminf(fminf(u[0][1], u[1][1]), fminf(u[2][1], u[3][1])); \
            float mq2 = fminf(fminf(u[0][2], u[1][2]), fminf(u[2][2], u[3][2])); \
            float mq3 = fminf(fminf(u[0][3], u[1][3]), fminf(u[2][3], u[3][3])); \
            float pa = fminf(mq0, DPPX1(mq0));                               \
            float pb = fminf(mq1, DPPX1(mq1));                               \
            float r01 = h0 ? pb : pa;                                        \
            pa = fminf(mq2, DPPX1(mq2));                                     \
            pb = fminf(mq3, DPPX1(mq3));                                     \
            float r23 = h0 ? pb : pa;                                        \
            pa = fminf(r01, DPPX2(r01));                                     \
            pb = fminf(r23, DPPX2(r23));                                     \
            mini4[fi] = h1 ? pb : pa;                                        \
        }                                                                    \
        {                                                                    \
            float pa = fminf(mini4[0], __shfl_xor(mini4[0], 4));             \
            float pb = fminf(mini4[1], __shfl_xor(mini4[1], 4));             \
            float A = h2 ? pb : pa;                                          \
            pa = fminf(mini4[2], __shfl_xor(mini4[2], 4));                   \
            pb = fminf(mini4[3], __shfl_xor(mini4[3], 4));                   \
            float B = h2 ? pb : pa;                                          \
            pa = fminf(A, __shfl_xor(A, 8));                                 \
            pb = fminf(B, __shfl_xor(B, 8));                                 \
            float Mi = h3 ? pb : pa;                                         \
            float dmin = __builtin_amdgcn_sqrtf(fmaxf(Mi, 0.f));             \
            int ii = ibase + ((rf >> 2) << 4) + (kg << 2) + (rf & 3);        \
            atomicMin(&sbm2[ii], __float_as_uint(dmin));                     \
        }                                                                    \
        {                                                                    \
            float pa = fminf(minj[0], __shfl_xor(minj[0], 32));              \
            float pb = fminf(minj[1], __shfl_xor(minj[1], 32));              \
            float A = h5 ? pb : pa;                                          \
            pa = fminf(minj[2], __shfl_xor(minj[2], 32));                    \
            pb = fminf(minj[3], __shfl_xor(minj[3], 32));                    \
            float B = h5 ? pb : pa;                                          \
            pa = fminf(A, __shfl_xor(A, 16));                                \
            pb = fminf(B, __shfl_xor(B, 16));                                \
            float Mj = h4 ? pb : pa;                                         \
            float dminj = __builtin_amdgcn_sqrtf(fmaxf(Mj, 0.f));            \
            int fjf = ((lane >> 5) & 1) | (((lane >> 4) & 1) << 1);          \
            atomicMin(&sbm1[jbase + (fjf << 4) + rf], __float_as_uint(dminj)); \
        }                                                                    \
    }

    // Final reduce for pair p. REINIT happens BEFORE the second barrier:
    // each tid<128 rewrites exactly the slots it just read (same-wave DS ops
    // are in order), and the lgkmcnt(0)+barrier then makes the re-init
    // globally visible before any pair-1 atomicMin.
#define REDUCE_OUT(p, REINIT)                                                \
    {                                                                        \
        LGKMBAR();                                                           \
        const int nn2 = n2v[p];                                              \
        float v = 0.f;                                                       \
        if (tid < 128) {                                                     \
            u32 m1b = sbm1[tid], m2b = sbm2[tid];                            \
            if (n1 > 0 && tid < nn2) v += __uint_as_float(m1b);              \
            if (nn2 > 0 && tid < n1) v += __uint_as_float(m2b);              \
            if (REINIT) {                                                    \
                sbm1[tid] = 0x7F800000u; sbm2[tid] = 0x7F800000u;            \
            }                                                                \
        }                                                                    \
        _Pragma("unroll")                                                    \
        for (int off = 32; off >= 1; off >>= 1) v += __shfl_down(v, off);    \
        if (lane == 0) swsum[wid] = v;                                       \
        LGKMBAR();                                                           \
        if (tid == 0) out[(b1 << 6) + b2base + (p)]                          \
            = swsum[0] + swsum[1] + swsum[2] + swsum[3];                     \
    }

    // ---- pair 0 (pair-1 q0/q1 staged before epilogue0 -> overlap) ----
    WAITV4(); BAR(); COMPUTE(0); BAR(); STAGE(0, gB0, 2);
    WAITV4(); BAR(); COMPUTE(1); BAR(); STAGE(1, gB0, 3);
    WAITV4(); BAR(); COMPUTE(0); BAR(); STAGE(0, gB1, 0);
    WAITV4(); BAR(); COMPUTE(1); BAR(); STAGE(1, gB1, 1);
    EPILOGUE(0);
    REDUCE_OUT(0, 1);

    // ---- pair 1 ----
#pragma unroll
    for (int fi = 0; fi < 4; ++fi)
#pragma unroll
        for (int fj = 0; fj < 4; ++fj)
            acc[fi][fj] = (f32x4){0.f, 0.f, 0.f, 0.f};

    WAITV4(); BAR(); COMPUTE(0); BAR(); STAGE(0, gB1, 2);
    WAITV4(); BAR(); COMPUTE(1); BAR(); STAGE(1, gB1, 3);
    WAITV4(); BAR(); COMPUTE(0); BAR();
    WAITV0(); BAR(); COMPUTE(1);
    EPILOGUE(1);
    REDUCE_OUT(1, 0);

#undef COMPUTE
#undef STAGE
#undef EPILOGUE
#undef REDUCE_OUT
#undef WAITV4
#undef WAITV0
#undef BAR
#undef LGKMBAR
}

extern "C" void kernel_launch(void* const* d_in, const int* in_sizes, int n_in,
                              void* d_out, int out_size, void* d_ws, size_t ws_size,
                              hipStream_t stream) {
    const float* v1  = (const float*)d_in[0];
    const int*   sz1 = (const int*)d_in[1];
    const float* v2  = (const float*)d_in[2];
    const int*   sz2 = (const int*)d_in[3];
    float* out = (float*)d_out;
    (void)in_sizes; (void)n_in; (void)out_size; (void)ws_size;

    char* ws = (char*)d_ws;
    ushort_t* v1b = (ushort_t*)ws;                       // 2 MB
    ushort_t* v2b = (ushort_t*)(ws + (2u << 20));        // 2 MB
    float*    x2g = (float*)(ws + (4u << 20));           // 32 KB
    float*    y2g = x2g + 64 * 128;                      // 32 KB

    softhd_pre<<<dim3(1024), dim3(256), 0, stream>>>(v1, v2, v1b, v2b, x2g, y2g);
    softhd_mfma<<<dim3(2048), dim3(256), 0, stream>>>(v1b, v2b, x2g, y2g,
                                                      sz1, sz2, out);
}

// Round 12
// 39.427 us; speedup vs baseline: 1.0009x; 1.0009x over previous
//
#include <hip/hip_runtime.h>
#include <math.h>

// SoftHd via bf16 MFMA — NO LDS staging: fragments load straight from the
// L2-resident quarter-blocked panels into VGPRs. 2 barriers per block total.
// out[b1,b2] = sum_{j<sz2} min_{i<sz1} dist[i,j] + sum_{i<sz1} min_{j<sz2} dist[i,j]
// dist via gemm identity on bf16-rounded inputs; sqrt monotone -> mins on
// squared distances, sqrt after reduction; masking folded into +INF operands.
// Quarter-blocked global bf16 layout (pre-kernel):
//   panel byte off(r,c16) = (c16>>2)*8192 + (r>>3)*512 + (c16&3)*128 + (r&7)*16
// Within a quarter q: off = (r>>3)*512 + kg*128 + (r&7)*16  (+ q*8192),
// exactly the MFMA fragment footprint -> per-wave loads are 8x128B segments.

typedef __attribute__((ext_vector_type(8))) short short8;
typedef __attribute__((ext_vector_type(4))) float f32x4;
typedef unsigned int u32;
typedef unsigned short ushort_t;

static __device__ __forceinline__ ushort_t f32_to_bf16_rne(float f) {
    u32 b = __float_as_uint(f);
    b += 0x7FFFu + ((b >> 16) & 1u);
    return (ushort_t)(b >> 16);
}

// DPP quad_perm folds (VALU pipe): xor1 = 0xB1, xor2 = 0x4E.
#define DPPX1(x) __int_as_float(__builtin_amdgcn_update_dpp( \
    0, __float_as_int(x), 0xB1, 0xF, 0xF, true))
#define DPPX2(x) __int_as_float(__builtin_amdgcn_update_dpp( \
    0, __float_as_int(x), 0x4E, 0xF, 0xF, true))

// ---------------------------------------------------------------------------
// Pre-kernel: f32 -> bf16 into quarter-blocked layout + per-row squared norms
// (fp32 of the ROUNDED values).
// ---------------------------------------------------------------------------
__global__ __launch_bounds__(256) void softhd_pre(
    const float* __restrict__ v1, const float* __restrict__ v2,
    ushort_t* __restrict__ v1b, ushort_t* __restrict__ v2b,
    float* __restrict__ x2g, float* __restrict__ y2g)
{
    int flat = blockIdx.x * 256 + threadIdx.x;
    int c = flat & 15;
    int r = (flat >> 4) & 127;
    int b = (flat >> 11) & 63;
    int t = flat >> 17;

    const float* src = (t ? v2 : v1) + ((size_t)((b << 7) + r) << 7) + c * 8;
    char* dstp = (char*)((t ? v2b : v1b) + ((size_t)b << 14));

    float4 q0 = *(const float4*)(src);
    float4 q1 = *(const float4*)(src + 4);

    ushort_t h[8];
    h[0] = f32_to_bf16_rne(q0.x); h[1] = f32_to_bf16_rne(q0.y);
    h[2] = f32_to_bf16_rne(q0.z); h[3] = f32_to_bf16_rne(q0.w);
    h[4] = f32_to_bf16_rne(q1.x); h[5] = f32_to_bf16_rne(q1.y);
    h[6] = f32_to_bf16_rne(q1.z); h[7] = f32_to_bf16_rne(q1.w);

    float p = 0.f;
#pragma unroll
    for (int k = 0; k < 8; ++k) {
        float fv = __uint_as_float((u32)h[k] << 16);
        p += fv * fv;
    }

    uint4 w;
    w.x = (u32)h[0] | ((u32)h[1] << 16);
    w.y = (u32)h[2] | ((u32)h[3] << 16);
    w.z = (u32)h[4] | ((u32)h[5] << 16);
    w.w = (u32)h[6] | ((u32)h[7] << 16);

    int off = ((c >> 2) << 13) + ((r >> 3) << 9) + ((c & 3) << 7) + ((r & 7) << 4);
    *(uint4*)(dstp + off) = w;

    p += __shfl_xor(p, 1);
    p += __shfl_xor(p, 2);
    p += __shfl_xor(p, 4);
    p += __shfl_xor(p, 8);
    if (c == 0) (t ? y2g : x2g)[(b << 7) + r] = p;
}

// ---------------------------------------------------------------------------
// Main kernel: one block per (b1,b2). 4 waves, 2x2 quadrant split (64x64 out
// per wave). Fragments read directly from global (L1/L2-resident panels);
// 2-quarter register pipeline; no main-loop barriers.
// ---------------------------------------------------------------------------
__global__ __launch_bounds__(256, 3) void softhd_mfma(
    const ushort_t* __restrict__ v1b, const ushort_t* __restrict__ v2b,
    const float* __restrict__ x2g, const float* __restrict__ y2g,
    const int* __restrict__ sz1, const int* __restrict__ sz2,
    float* __restrict__ out)
{
    __shared__ float sx2[128], sy2[128];
    __shared__ u32 sbm1[128], sbm2[128];
    __shared__ float swsum[4];

    const int tid = threadIdx.x;
    const int lane = tid & 63;
    const int wid = tid >> 6;
    // XCD-bijective swizzle (4096 % 8 == 0): contiguous bid range per XCD ->
    // shared b1-stripe A panel + v2b (2 MB) resident in that XCD's L2.
    const int bid = ((blockIdx.x & 7) << 9) | (blockIdx.x >> 3);
    const int b1 = bid >> 6, b2 = bid & 63;

    const char* gA = (const char*)(v1b + ((size_t)b1 << 14));
    const char* gB = (const char*)(v2b + ((size_t)b2 << 14));

    const int n1 = min(max(sz1[b1], 0), 128);
    const int n2 = min(max(sz2[b2], 0), 128);

    if (tid < 128) {
        sx2[tid] = x2g[(b1 << 7) + tid];
        sbm1[tid] = 0x7F800000u;            // +inf bits
    } else {
        sy2[tid - 128] = y2g[(b2 << 7) + (tid - 128)];
        sbm2[tid - 128] = 0x7F800000u;
    }
    __syncthreads();                        // barrier #1 (init visible)

    const int qr = wid >> 1, qc = wid & 1;
    const int ibase = qr << 6, jbase = qc << 6;
    const int rf = lane & 15, kg = lane >> 4;
    const bool h0 = lane & 1, h1 = lane & 2, h2 = lane & 4, h3 = lane & 8;
    const bool h4 = lane & 16, h5 = lane & 32;

    // Per-fragment byte offsets within a quarter block (add q*8192 for quarter q).
    int aoff[4], boff[4];
#pragma unroll
    for (int f = 0; f < 4; ++f) {
        int ra = ibase + (f << 4) + rf;
        int rb = jbase + (f << 4) + rf;
        aoff[f] = ((ra >> 3) << 9) + (kg << 7) + ((ra & 7) << 4);
        boff[f] = ((rb >> 3) << 9) + (kg << 7) + ((rb & 7) << 4);
    }

    f32x4 acc[4][4];
#pragma unroll
    for (int fi = 0; fi < 4; ++fi)
#pragma unroll
        for (int fj = 0; fj < 4; ++fj)
            acc[fi][fj] = (f32x4){0.f, 0.f, 0.f, 0.f};

#define LOADQ(A, B, q)                                                       \
    {                                                                        \
        _Pragma("unroll")                                                    \
        for (int f = 0; f < 4; ++f) {                                        \
            A[f] = *(const short8*)(gA + ((q) << 13) + aoff[f]);             \
            B[f] = *(const short8*)(gB + ((q) << 13) + boff[f]);             \
        }                                                                    \
    }
#define MFMAQ(A, B)                                                          \
    {                                                                        \
        _Pragma("unroll")                                                    \
        for (int fi = 0; fi < 4; ++fi)                                       \
            _Pragma("unroll")                                                \
            for (int fj = 0; fj < 4; ++fj)                                   \
                acc[fi][fj] = __builtin_amdgcn_mfma_f32_16x16x32_bf16(       \
                    A[fi], B[fj], acc[fi][fj], 0, 0, 0);                     \
    }

    // 2-quarter-deep register pipeline, no barriers.
    short8 arA[4], brA[4], arB[4], brB[4];
    LOADQ(arA, brA, 0);
    LOADQ(arB, brB, 1);
    MFMAQ(arA, brA);
    LOADQ(arA, brA, 2);
    MFMAQ(arB, brB);
    LOADQ(arB, brB, 3);
    MFMAQ(arA, brA);
    MFMAQ(arB, brB);
#undef LOADQ
#undef MFMAQ

    const float INF = __builtin_inff();

    // ---- epilogue (R10-verified): u = x2+y2-2xy; DPP folds bits 0-1,
    // shfl folds bits 2-3 (mini) and 5,4 (minj); sqrt after reduction. ----
    float yje[4];
#pragma unroll
    for (int fj = 0; fj < 4; ++fj) {
        int j = jbase + (fj << 4) + rf;
        yje[fj] = (j < n2) ? sy2[j] : INF;
    }
    float minj[4] = {INF, INF, INF, INF};
    float mini4[4];
#pragma unroll
    for (int fi = 0; fi < 4; ++fi) {
        const int i0 = ibase + (fi << 4) + (kg << 2);
        float4 xs = *(const float4*)&sx2[i0];
        float xie[4];
        xie[0] = (i0 + 0 < n1) ? xs.x : INF;
        xie[1] = (i0 + 1 < n1) ? xs.y : INF;
        xie[2] = (i0 + 2 < n1) ? xs.z : INF;
        xie[3] = (i0 + 3 < n1) ? xs.w : INF;
        float u[4][4];
#pragma unroll
        for (int fj = 0; fj < 4; ++fj) {
#pragma unroll
            for (int q = 0; q < 4; ++q)
                u[fj][q] = fmaf(acc[fi][fj][q], -2.f, xie[q] + yje[fj]);
            minj[fj] = fminf(fminf(minj[fj], u[fj][0]), u[fj][1]);
            minj[fj] = fminf(fminf(minj[fj], u[fj][2]), u[fj][3]);
        }
        float mq0 = fminf(fminf(u[0][0], u[1][0]), fminf(u[2][0], u[3][0]));
        float mq1 = fminf(fminf(u[0][1], u[1][1]), fminf(u[2][1], u[3][1]));
        float mq2 = fminf(fminf(u[0][2], u[1][2]), fminf(u[2][2], u[3][2]));
        float mq3 = fminf(fminf(u[0][3], u[1][3]), fminf(u[2][3], u[3][3]));
        float pa = fminf(mq0, DPPX1(mq0));
        float pb = fminf(mq1, DPPX1(mq1));
        float r01 = h0 ? pb : pa;
        pa = fminf(mq2, DPPX1(mq2));
        pb = fminf(mq3, DPPX1(mq3));
        float r23 = h0 ? pb : pa;
        pa = fminf(r01, DPPX2(r01));
        pb = fminf(r23, DPPX2(r23));
        mini4[fi] = h1 ? pb : pa;
    }
    {
        float pa = fminf(mini4[0], __shfl_xor(mini4[0], 4));
        float pb = fminf(mini4[1], __shfl_xor(mini4[1], 4));
        float A = h2 ? pb : pa;
        pa = fminf(mini4[2], __shfl_xor(mini4[2], 4));
        pb = fminf(mini4[3], __shfl_xor(mini4[3], 4));
        float B = h2 ? pb : pa;
        pa = fminf(A, __shfl_xor(A, 8));
        pb = fminf(B, __shfl_xor(B, 8));
        float Mi = h3 ? pb : pa;
        float dmin = __builtin_amdgcn_sqrtf(fmaxf(Mi, 0.f));
        int ii = ibase + ((rf >> 2) << 4) + (kg << 2) + (rf & 3);
        atomicMin(&sbm2[ii], __float_as_uint(dmin));
    }
    {
        float pa = fminf(minj[0], __shfl_xor(minj[0], 32));
        float pb = fminf(minj[1], __shfl_xor(minj[1], 32));
        float A = h5 ? pb : pa;
        pa = fminf(minj[2], __shfl_xor(minj[2], 32));
        pb = fminf(minj[3], __shfl_xor(minj[3], 32));
        float B = h5 ? pb : pa;
        pa = fminf(A, __shfl_xor(A, 16));
        pb = fminf(B, __shfl_xor(B, 16));
        float Mj = h4 ? pb : pa;
        float dminj = __builtin_amdgcn_sqrtf(fmaxf(Mj, 0.f));
        int fjf = ((lane >> 5) & 1) | (((lane >> 4) & 1) << 1);
        atomicMin(&sbm1[jbase + (fjf << 4) + rf], __float_as_uint(dminj));
    }
    __syncthreads();                        // barrier #2 (atomics visible)

    float v = 0.f;
    if (tid < 128) {
        if (n1 > 0 && tid < n2) v += __uint_as_float(sbm1[tid]);
        if (n2 > 0 && tid < n1) v += __uint_as_float(sbm2[tid]);
    }
#pragma unroll
    for (int off = 32; off >= 1; off >>= 1) v += __shfl_down(v, off);
    if (lane == 0) swsum[wid] = v;
    __syncthreads();
    if (tid == 0) out[bid] = swsum[0] + swsum[1] + swsum[2] + swsum[3];
}

extern "C" void kernel_launch(void* const* d_in, const int* in_sizes, int n_in,
                              void* d_out, int out_size, void* d_ws, size_t ws_size,
                              hipStream_t stream) {
    const float* v1  = (const float*)d_in[0];
    const int*   sz1 = (const int*)d_in[1];
    const float* v2  = (const float*)d_in[2];
    const int*   sz2 = (const int*)d_in[3];
    float* out = (float*)d_out;
    (void)in_sizes; (void)n_in; (void)out_size; (void)ws_size;

    char* ws = (char*)d_ws;
    ushort_t* v1b = (ushort_t*)ws;                       // 2 MB
    ushort_t* v2b = (ushort_t*)(ws + (2u << 20));        // 2 MB
    float*    x2g = (float*)(ws + (4u << 20));           // 32 KB
    float*    y2g = x2g + 64 * 128;                      // 32 KB

    softhd_pre<<<dim3(1024), dim3(256), 0, stream>>>(v1, v2, v1b, v2b, x2g, y2g);
    softhd_mfma<<<dim3(4096), dim3(256), 0, stream>>>(v1b, v2b, x2g, y2g,
                                                      sz1, sz2, out);
}

// Round 13
// 35.037 us; speedup vs baseline: 1.1263x; 1.1253x over previous
//
#include <hip/hip_runtime.h>
#include <math.h>

// SoftHd via bf16 MFMA. R8 skeleton (counted-vmcnt K-quarter pipeline, best
// measured) + DPP/VALU-pipe epilogue folds + s_setprio around MFMA.
// out[b1,b2] = sum_{j<sz2} min_{i<sz1} dist[i,j] + sum_{i<sz1} min_{j<sz2} dist[i,j]
// dist via gemm identity on bf16-rounded inputs; sqrt monotone -> mins on
// squared distances, sqrt after reduction; masking folded into +INF operands.
// Quarter-blocked global bf16 layout (pre-kernel):
//   panel byte off(r,c16) = (c16>>2)*8192 + (r>>3)*512 + (c16&3)*128 + (r&7)*16

typedef __attribute__((ext_vector_type(8))) short short8;
typedef __attribute__((ext_vector_type(4))) float f32x4;
typedef unsigned int u32;
typedef unsigned short ushort_t;

static __device__ __forceinline__ ushort_t f32_to_bf16_rne(float f) {
    u32 b = __float_as_uint(f);
    b += 0x7FFFu + ((b >> 16) & 1u);
    return (ushort_t)(b >> 16);
}

// DPP quad_perm folds (VALU pipe): xor1 = 0xB1, xor2 = 0x4E.
#define DPPX1(x) __int_as_float(__builtin_amdgcn_update_dpp( \
    0, __float_as_int(x), 0xB1, 0xF, 0xF, true))
#define DPPX2(x) __int_as_float(__builtin_amdgcn_update_dpp( \
    0, __float_as_int(x), 0x4E, 0xF, 0xF, true))

// ---------------------------------------------------------------------------
// Pre-kernel: f32 -> bf16 into quarter-blocked layout + per-row squared norms
// (fp32 of the ROUNDED values).
// ---------------------------------------------------------------------------
__global__ __launch_bounds__(256) void softhd_pre(
    const float* __restrict__ v1, const float* __restrict__ v2,
    ushort_t* __restrict__ v1b, ushort_t* __restrict__ v2b,
    float* __restrict__ x2g, float* __restrict__ y2g)
{
    int flat = blockIdx.x * 256 + threadIdx.x;
    int c = flat & 15;
    int r = (flat >> 4) & 127;
    int b = (flat >> 11) & 63;
    int t = flat >> 17;

    const float* src = (t ? v2 : v1) + ((size_t)((b << 7) + r) << 7) + c * 8;
    char* dstp = (char*)((t ? v2b : v1b) + ((size_t)b << 14));

    float4 q0 = *(const float4*)(src);
    float4 q1 = *(const float4*)(src + 4);

    ushort_t h[8];
    h[0] = f32_to_bf16_rne(q0.x); h[1] = f32_to_bf16_rne(q0.y);
    h[2] = f32_to_bf16_rne(q0.z); h[3] = f32_to_bf16_rne(q0.w);
    h[4] = f32_to_bf16_rne(q1.x); h[5] = f32_to_bf16_rne(q1.y);
    h[6] = f32_to_bf16_rne(q1.z); h[7] = f32_to_bf16_rne(q1.w);

    float p = 0.f;
#pragma unroll
    for (int k = 0; k < 8; ++k) {
        float fv = __uint_as_float((u32)h[k] << 16);
        p += fv * fv;
    }

    uint4 w;
    w.x = (u32)h[0] | ((u32)h[1] << 16);
    w.y = (u32)h[2] | ((u32)h[3] << 16);
    w.z = (u32)h[4] | ((u32)h[5] << 16);
    w.w = (u32)h[6] | ((u32)h[7] << 16);

    int off = ((c >> 2) << 13) + ((r >> 3) << 9) + ((c & 3) << 7) + ((r & 7) << 4);
    *(uint4*)(dstp + off) = w;

    p += __shfl_xor(p, 1);
    p += __shfl_xor(p, 2);
    p += __shfl_xor(p, 4);
    p += __shfl_xor(p, 8);
    if (c == 0) (t ? y2g : x2g)[(b << 7) + r] = p;
}

// ---------------------------------------------------------------------------
// Main kernel.
// ---------------------------------------------------------------------------
__global__ __launch_bounds__(256, 4) void softhd_mfma(
    const ushort_t* __restrict__ v1b, const ushort_t* __restrict__ v2b,
    const float* __restrict__ x2g, const float* __restrict__ y2g,
    const int* __restrict__ sz1, const int* __restrict__ sz2,
    float* __restrict__ out)
{
    __shared__ __align__(16) ushort_t sb[2][2][4096];  // [buf][panel][8 KB]
    __shared__ float sx2[128], sy2[128];
    __shared__ u32 sbm1[128], sbm2[128];
    __shared__ float swsum[4];

    const int tid = threadIdx.x;
    const int lane = tid & 63;
    const int wid = tid >> 6;
    // XCD-bijective swizzle (4096 % 8 == 0).
    const int bid = ((blockIdx.x & 7) << 9) | (blockIdx.x >> 3);
    const int b1 = bid >> 6, b2 = bid & 63;

    const char* gp0 = (const char*)(v1b + ((size_t)b1 << 14));
    const char* gp1 = (const char*)(v2b + ((size_t)b2 << 14));

    const int n1 = min(max(sz1[b1], 0), 128);
    const int n2 = min(max(sz2[b2], 0), 128);

    // Norm loads + LDS init first, fully retired before any STAGE issues.
    if (tid < 128) {
        sx2[tid] = x2g[(b1 << 7) + tid];
        sbm1[tid] = 0x7F800000u;            // +inf bits
    } else {
        sy2[tid - 128] = y2g[(b2 << 7) + (tid - 128)];
        sbm2[tid - 128] = 0x7F800000u;
    }
    asm volatile("" ::: "memory");          // pin order: init before staging

#define STAGE(d, q)                                                          \
    {                                                                        \
        _Pragma("unroll")                                                    \
        for (int e = 0; e < 2; ++e) {                                        \
            int m16 = ((e << 8) + tid) << 4;                                 \
            __builtin_amdgcn_global_load_lds(                                \
                (const __attribute__((address_space(1))) u32*)(gp0 + ((q) << 13) + m16), \
                (__attribute__((address_space(3))) u32*)((char*)&sb[d][0][0] + m16),     \
                16, 0, 0);                                                   \
            __builtin_amdgcn_global_load_lds(                                \
                (const __attribute__((address_space(1))) u32*)(gp1 + ((q) << 13) + m16), \
                (__attribute__((address_space(3))) u32*)((char*)&sb[d][1][0] + m16),     \
                16, 0, 0);                                                   \
        }                                                                    \
    }
#define WAITV4()  asm volatile("s_waitcnt vmcnt(4)" ::: "memory")
#define WAITV0()  asm volatile("s_waitcnt vmcnt(0)" ::: "memory")
#define BAR()     asm volatile("s_barrier" ::: "memory")

    STAGE(0, 0);                             // 4 loads/thread
    STAGE(1, 1);                             // +4 -> 8 in flight

    const int qr = wid >> 1, qc = wid & 1;
    const int ibase = qr << 6, jbase = qc << 6;
    const int rf = lane & 15, kg = lane >> 4;
    const bool h0 = lane & 1, h1 = lane & 2, h2 = lane & 4, h3 = lane & 8;
    const bool h4 = lane & 16, h5 = lane & 32;

    // frag elem offsets within an 8 KB quarter: (row>>3)*256 + kg*64 + (row&7)*8
    int aoff[4], boff[4];
#pragma unroll
    for (int f = 0; f < 4; ++f) {
        int ra = ibase + (f << 4) + rf;
        int rb = jbase + (f << 4) + rf;
        aoff[f] = ((ra >> 3) << 8) + (kg << 6) + ((ra & 7) << 3);
        boff[f] = ((rb >> 3) << 8) + (kg << 6) + ((rb & 7) << 3);
    }

    f32x4 acc[4][4];
#pragma unroll
    for (int fi = 0; fi < 4; ++fi)
#pragma unroll
        for (int fj = 0; fj < 4; ++fj)
            acc[fi][fj] = (f32x4){0.f, 0.f, 0.f, 0.f};

#define COMPUTE(d)                                                           \
    {                                                                        \
        short8 a[4], b[4];                                                   \
        _Pragma("unroll")                                                    \
        for (int f = 0; f < 4; ++f) {                                        \
            a[f] = *(const short8*)(&sb[d][0][0] + aoff[f]);                 \
            b[f] = *(const short8*)(&sb[d][1][0] + boff[f]);                 \
        }                                                                    \
        __builtin_amdgcn_s_setprio(1);                                       \
        _Pragma("unroll")                                                    \
        for (int fi = 0; fi < 4; ++fi)                                       \
            _Pragma("unroll")                                                \
            for (int fj = 0; fj < 4; ++fj)                                   \
                acc[fi][fj] = __builtin_amdgcn_mfma_f32_16x16x32_bf16(       \
                    a[fi], b[fj], acc[fi][fj], 0, 0, 0);                     \
        __builtin_amdgcn_s_setprio(0);                                       \
    }

    // q0: wait own loads (q1 stays in flight), compute, then refill buf0.
    WAITV4(); BAR();
    COMPUTE(0);
    BAR(); STAGE(0, 2);
    // q1
    WAITV4(); BAR();
    COMPUTE(1);
    BAR(); STAGE(1, 3);
    // q2
    WAITV4(); BAR();
    COMPUTE(0);
    BAR();
    // q3 (last: drain)
    WAITV0(); BAR();
    COMPUTE(1);

#undef COMPUTE
#undef STAGE
#undef WAITV4
#undef WAITV0
#undef BAR

    const float INF = __builtin_inff();

    // ---- DPP epilogue (verified in R10/R12): u = x2+y2-2xy; DPP folds lane
    // bits 0-1, shfl folds bits 2-3 (mini) and 5,4 (minj); sqrt after. ----
    float yje[4];
#pragma unroll
    for (int fj = 0; fj < 4; ++fj) {
        int j = jbase + (fj << 4) + rf;
        yje[fj] = (j < n2) ? sy2[j] : INF;
    }
    float minj[4] = {INF, INF, INF, INF};
    float mini4[4];
#pragma unroll
    for (int fi = 0; fi < 4; ++fi) {
        const int i0 = ibase + (fi << 4) + (kg << 2);
        float4 xs = *(const float4*)&sx2[i0];
        float xie[4];
        xie[0] = (i0 + 0 < n1) ? xs.x : INF;
        xie[1] = (i0 + 1 < n1) ? xs.y : INF;
        xie[2] = (i0 + 2 < n1) ? xs.z : INF;
        xie[3] = (i0 + 3 < n1) ? xs.w : INF;
        float u[4][4];
#pragma unroll
        for (int fj = 0; fj < 4; ++fj) {
#pragma unroll
            for (int q = 0; q < 4; ++q)
                u[fj][q] = fmaf(acc[fi][fj][q], -2.f, xie[q] + yje[fj]);
            minj[fj] = fminf(fminf(minj[fj], u[fj][0]), u[fj][1]);
            minj[fj] = fminf(fminf(minj[fj], u[fj][2]), u[fj][3]);
        }
        float mq0 = fminf(fminf(u[0][0], u[1][0]), fminf(u[2][0], u[3][0]));
        float mq1 = fminf(fminf(u[0][1], u[1][1]), fminf(u[2][1], u[3][1]));
        float mq2 = fminf(fminf(u[0][2], u[1][2]), fminf(u[2][2], u[3][2]));
        float mq3 = fminf(fminf(u[0][3], u[1][3]), fminf(u[2][3], u[3][3]));
        float pa = fminf(mq0, DPPX1(mq0));
        float pb = fminf(mq1, DPPX1(mq1));
        float r01 = h0 ? pb : pa;
        pa = fminf(mq2, DPPX1(mq2));
        pb = fminf(mq3, DPPX1(mq3));
        float r23 = h0 ? pb : pa;
        pa = fminf(r01, DPPX2(r01));
        pb = fminf(r23, DPPX2(r23));
        mini4[fi] = h1 ? pb : pa;
    }
    {
        float pa = fminf(mini4[0], __shfl_xor(mini4[0], 4));
        float pb = fminf(mini4[1], __shfl_xor(mini4[1], 4));
        float A = h2 ? pb : pa;
        pa = fminf(mini4[2], __shfl_xor(mini4[2], 4));
        pb = fminf(mini4[3], __shfl_xor(mini4[3], 4));
        float B = h2 ? pb : pa;
        pa = fminf(A, __shfl_xor(A, 8));
        pb = fminf(B, __shfl_xor(B, 8));
        float Mi = h3 ? pb : pa;
        float dmin = __builtin_amdgcn_sqrtf(fmaxf(Mi, 0.f));
        int ii = ibase + ((rf >> 2) << 4) + (kg << 2) + (rf & 3);
        atomicMin(&sbm2[ii], __float_as_uint(dmin));
    }
    {
        float pa = fminf(minj[0], __shfl_xor(minj[0], 32));
        float pb = fminf(minj[1], __shfl_xor(minj[1], 32));
        float A = h5 ? pb : pa;
        pa = fminf(minj[2], __shfl_xor(minj[2], 32));
        pb = fminf(minj[3], __shfl_xor(minj[3], 32));
        float B = h5 ? pb : pa;
        pa = fminf(A, __shfl_xor(A, 16));
        pb = fminf(B, __shfl_xor(B, 16));
        float Mj = h4 ? pb : pa;
        float dminj = __builtin_amdgcn_sqrtf(fmaxf(Mj, 0.f));
        int fjf = ((lane >> 5) & 1) | (((lane >> 4) & 1) << 1);
        atomicMin(&sbm1[jbase + (fjf << 4) + rf], __float_as_uint(dminj));
    }
    __syncthreads();

    float v = 0.f;
    if (tid < 128) {
        if (n1 > 0 && tid < n2) v += __uint_as_float(sbm1[tid]);
        if (n2 > 0 && tid < n1) v += __uint_as_float(sbm2[tid]);
    }
#pragma unroll
    for (int off = 32; off >= 1; off >>= 1) v += __shfl_down(v, off);
    if (lane == 0) swsum[wid] = v;
    __syncthreads();
    if (tid == 0) out[bid] = swsum[0] + swsum[1] + swsum[2] + swsum[3];
}

extern "C" void kernel_launch(void* const* d_in, const int* in_sizes, int n_in,
                              void* d_out, int out_size, void* d_ws, size_t ws_size,
                              hipStream_t stream) {
    const float* v1  = (const float*)d_in[0];
    const int*   sz1 = (const int*)d_in[1];
    const float* v2  = (const float*)d_in[2];
    const int*   sz2 = (const int*)d_in[3];
    float* out = (float*)d_out;
    (void)in_sizes; (void)n_in; (void)out_size; (void)ws_size;

    char* ws = (char*)d_ws;
    ushort_t* v1b = (ushort_t*)ws;                       // 2 MB
    ushort_t* v2b = (ushort_t*)(ws + (2u << 20));        // 2 MB
    float*    x2g = (float*)(ws + (4u << 20));           // 32 KB
    float*    y2g = x2g + 64 * 128;                      // 32 KB

    softhd_pre<<<dim3(1024), dim3(256), 0, stream>>>(v1, v2, v1b, v2b, x2g, y2g);
    softhd_mfma<<<dim3(4096), dim3(256), 0, stream>>>(v1b, v2b, x2g, y2g,
                                                      sz1, sz2, out);
}

// Round 14
// 33.896 us; speedup vs baseline: 1.1642x; 1.0337x over previous
//
#include <hip/hip_runtime.h>
#include <math.h>

// SoftHd via bf16 MFMA. 2 b2-panels per block with A staged ONCE (persists in
// LDS), B double-buffered; counted-vmcnt ladder; setprio; DPP epilogue;
// single end-of-kernel reduce (per-pair sbm arrays, no mid-kernel barriers).
// out[b1,b2] = sum_{j<sz2} min_{i<sz1} dist[i,j] + sum_{i<sz1} min_{j<sz2} dist[i,j]
// dist via gemm identity on bf16-rounded inputs; sqrt monotone -> mins on
// squared distances, sqrt after reduction; masking folded into +INF operands.
// Quarter-blocked global bf16 layout (pre-kernel):
//   panel byte off(r,c16) = (c16>>2)*8192 + (r>>3)*512 + (c16&3)*128 + (r&7)*16

typedef __attribute__((ext_vector_type(8))) short short8;
typedef __attribute__((ext_vector_type(4))) float f32x4;
typedef unsigned int u32;
typedef unsigned short ushort_t;

static __device__ __forceinline__ ushort_t f32_to_bf16_rne(float f) {
    u32 b = __float_as_uint(f);
    b += 0x7FFFu + ((b >> 16) & 1u);
    return (ushort_t)(b >> 16);
}

// DPP quad_perm folds (VALU pipe): xor1 = 0xB1, xor2 = 0x4E.
#define DPPX1(x) __int_as_float(__builtin_amdgcn_update_dpp( \
    0, __float_as_int(x), 0xB1, 0xF, 0xF, true))
#define DPPX2(x) __int_as_float(__builtin_amdgcn_update_dpp( \
    0, __float_as_int(x), 0x4E, 0xF, 0xF, true))

// ---------------------------------------------------------------------------
// Pre-kernel: f32 -> bf16 into quarter-blocked layout + per-row squared norms
// (fp32 of the ROUNDED values).
// ---------------------------------------------------------------------------
__global__ __launch_bounds__(256) void softhd_pre(
    const float* __restrict__ v1, const float* __restrict__ v2,
    ushort_t* __restrict__ v1b, ushort_t* __restrict__ v2b,
    float* __restrict__ x2g, float* __restrict__ y2g)
{
    int flat = blockIdx.x * 256 + threadIdx.x;
    int c = flat & 15;
    int r = (flat >> 4) & 127;
    int b = (flat >> 11) & 63;
    int t = flat >> 17;

    const float* src = (t ? v2 : v1) + ((size_t)((b << 7) + r) << 7) + c * 8;
    char* dstp = (char*)((t ? v2b : v1b) + ((size_t)b << 14));

    float4 q0 = *(const float4*)(src);
    float4 q1 = *(const float4*)(src + 4);

    ushort_t h[8];
    h[0] = f32_to_bf16_rne(q0.x); h[1] = f32_to_bf16_rne(q0.y);
    h[2] = f32_to_bf16_rne(q0.z); h[3] = f32_to_bf16_rne(q0.w);
    h[4] = f32_to_bf16_rne(q1.x); h[5] = f32_to_bf16_rne(q1.y);
    h[6] = f32_to_bf16_rne(q1.z); h[7] = f32_to_bf16_rne(q1.w);

    float p = 0.f;
#pragma unroll
    for (int k = 0; k < 8; ++k) {
        float fv = __uint_as_float((u32)h[k] << 16);
        p += fv * fv;
    }

    uint4 w;
    w.x = (u32)h[0] | ((u32)h[1] << 16);
    w.y = (u32)h[2] | ((u32)h[3] << 16);
    w.z = (u32)h[4] | ((u32)h[5] << 16);
    w.w = (u32)h[6] | ((u32)h[7] << 16);

    int off = ((c >> 2) << 13) + ((r >> 3) << 9) + ((c & 3) << 7) + ((r & 7) << 4);
    *(uint4*)(dstp + off) = w;

    p += __shfl_xor(p, 1);
    p += __shfl_xor(p, 2);
    p += __shfl_xor(p, 4);
    p += __shfl_xor(p, 8);
    if (c == 0) (t ? y2g : x2g)[(b << 7) + r] = p;
}

// ---------------------------------------------------------------------------
// Main kernel: 2048 blocks = 64 b1 x 32 b2-pairs. 4 waves, 2x2 quadrant split
// per pair (64x64 out per wave). A panel (32 KB) staged once, persists.
// ---------------------------------------------------------------------------
__global__ __launch_bounds__(256, 3) void softhd_mfma(
    const ushort_t* __restrict__ v1b, const ushort_t* __restrict__ v2b,
    const float* __restrict__ x2g, const float* __restrict__ y2g,
    const int* __restrict__ sz1, const int* __restrict__ sz2,
    float* __restrict__ out)
{
    __shared__ __align__(16) ushort_t sA[4 * 4096];    // full A panel, 32 KB
    __shared__ __align__(16) ushort_t sB[2][4096];     // B quarter dbuf, 16 KB
    __shared__ float sx2[128], sy2[2][128];
    __shared__ u32 sbm1[2][128], sbm2[2][128];
    __shared__ float swsum[4];

    const int tid = threadIdx.x;
    const int lane = tid & 63;
    const int wid = tid >> 6;
    // XCD-bijective swizzle (2048 % 8 == 0).
    const int bid = ((blockIdx.x & 7) << 8) | (blockIdx.x >> 3);
    const int b1 = bid >> 5;
    const int b2base = (bid & 31) << 1;

    const char* gA = (const char*)(v1b + ((size_t)b1 << 14));
    const char* gB0 = (const char*)(v2b + ((size_t)(b2base + 0) << 14));
    const char* gB1 = (const char*)(v2b + ((size_t)(b2base + 1) << 14));

    const int n1 = min(max(sz1[b1], 0), 128);
    int n2v[2];
    n2v[0] = min(max(sz2[b2base + 0], 0), 128);
    n2v[1] = min(max(sz2[b2base + 1], 0), 128);

    // Norm loads + LDS init first, fully retired before any STAGE issues.
    if (tid < 128) {
        sx2[tid] = x2g[(b1 << 7) + tid];
    } else {
        sy2[0][tid - 128] = y2g[((b2base + 0) << 7) + (tid - 128)];
        sy2[1][tid - 128] = y2g[((b2base + 1) << 7) + (tid - 128)];
    }
    ((u32*)sbm1)[tid] = 0x7F800000u;        // +inf bits (2x128 slots)
    ((u32*)sbm2)[tid] = 0x7F800000u;
    asm volatile("" ::: "memory");          // pin order: init before staging

    // A panel: 32 KB linear copy, 8 x 16B per thread.
#define STAGE_A()                                                            \
    {                                                                        \
        _Pragma("unroll")                                                    \
        for (int e = 0; e < 8; ++e) {                                        \
            int m16 = ((e << 8) + tid) << 4;                                 \
            __builtin_amdgcn_global_load_lds(                                \
                (const __attribute__((address_space(1))) u32*)(gA + m16),    \
                (__attribute__((address_space(3))) u32*)((char*)&sA[0] + m16),\
                16, 0, 0);                                                   \
        }                                                                    \
    }
// One B quarter (8 KB) into buffer d: 2 x 16B per thread.
#define STAGE_B(d, gB, q)                                                    \
    {                                                                        \
        _Pragma("unroll")                                                    \
        for (int e = 0; e < 2; ++e) {                                        \
            int m16 = ((e << 8) + tid) << 4;                                 \
            __builtin_amdgcn_global_load_lds(                                \
                (const __attribute__((address_space(1))) u32*)((gB) + ((q) << 13) + m16),\
                (__attribute__((address_space(3))) u32*)((char*)&sB[d][0] + m16),        \
                16, 0, 0);                                                   \
        }                                                                    \
    }
#define WAITV2()  asm volatile("s_waitcnt vmcnt(2)" ::: "memory")
#define WAITV0()  asm volatile("s_waitcnt vmcnt(0)" ::: "memory")
#define BAR()     asm volatile("s_barrier" ::: "memory")

    STAGE_A();                 // 8 loads/thread
    STAGE_B(0, gB0, 0);        // +2
    STAGE_B(1, gB0, 1);        // +2 -> 12 in flight

    const int qr = wid >> 1, qc = wid & 1;
    const int ibase = qr << 6, jbase = qc << 6;
    const int rf = lane & 15, kg = lane >> 4;
    const bool h0 = lane & 1, h1 = lane & 2, h2 = lane & 4, h3 = lane & 8;
    const bool h4 = lane & 16, h5 = lane & 32;

    // frag elem offsets within an 8 KB quarter: (row>>3)*256 + kg*64 + (row&7)*8
    int aoff[4], boff[4];
#pragma unroll
    for (int f = 0; f < 4; ++f) {
        int ra = ibase + (f << 4) + rf;
        int rb = jbase + (f << 4) + rf;
        aoff[f] = ((ra >> 3) << 8) + (kg << 6) + ((ra & 7) << 3);
        boff[f] = ((rb >> 3) << 8) + (kg << 6) + ((rb & 7) << 3);
    }

    f32x4 acc[4][4];
#pragma unroll
    for (int fi = 0; fi < 4; ++fi)
#pragma unroll
        for (int fj = 0; fj < 4; ++fj)
            acc[fi][fj] = (f32x4){0.f, 0.f, 0.f, 0.f};

    // A from the persistent panel (quarter q), B from dbuf d.
#define COMPUTE(d, q)                                                        \
    {                                                                        \
        short8 a[4], b[4];                                                   \
        _Pragma("unroll")                                                    \
        for (int f = 0; f < 4; ++f) {                                        \
            a[f] = *(const short8*)(&sA[(q) << 12] + aoff[f]);               \
            b[f] = *(const short8*)(&sB[d][0] + boff[f]);                    \
        }                                                                    \
        __builtin_amdgcn_s_setprio(1);                                       \
        _Pragma("unroll")                                                    \
        for (int fi = 0; fi < 4; ++fi)                                       \
            _Pragma("unroll")                                                \
            for (int fj = 0; fj < 4; ++fj)                                   \
                acc[fi][fj] = __builtin_amdgcn_mfma_f32_16x16x32_bf16(       \
                    a[fi], b[fj], acc[fi][fj], 0, 0, 0);                     \
        __builtin_amdgcn_s_setprio(0);                                       \
    }

    const float INF = __builtin_inff();

    // DPP epilogue (R13-verified), pair-indexed sbm/sy2/n2.
#define EPILOGUE(p)                                                          \
    {                                                                        \
        const int nn2 = n2v[p];                                              \
        float yje[4];                                                        \
        _Pragma("unroll")                                                    \
        for (int fj = 0; fj < 4; ++fj) {                                     \
            int j = jbase + (fj << 4) + rf;                                  \
            yje[fj] = (j < nn2) ? sy2[p][j] : INF;                           \
        }                                                                    \
        float minj[4] = {INF, INF, INF, INF};                                \
        float mini4[4];                                                      \
        _Pragma("unroll")                                                    \
        for (int fi = 0; fi < 4; ++fi) {                                     \
            const int i0 = ibase + (fi << 4) + (kg << 2);                    \
            float4 xs = *(const float4*)&sx2[i0];                            \
            float xie[4];                                                    \
            xie[0] = (i0 + 0 < n1) ? xs.x : INF;                             \
            xie[1] = (i0 + 1 < n1) ? xs.y : INF;                             \
            xie[2] = (i0 + 2 < n1) ? xs.z : INF;                             \
            xie[3] = (i0 + 3 < n1) ? xs.w : INF;                             \
            float u[4][4];                                                   \
            _Pragma("unroll")                                                \
            for (int fj = 0; fj < 4; ++fj) {                                 \
                _Pragma("unroll")                                            \
                for (int q = 0; q < 4; ++q)                                  \
                    u[fj][q] = fmaf(acc[fi][fj][q], -2.f, xie[q] + yje[fj]); \
                minj[fj] = fminf(fminf(minj[fj], u[fj][0]), u[fj][1]);       \
                minj[fj] = fminf(fminf(minj[fj], u[fj][2]), u[fj][3]);       \
            }                                                                \
            float mq0 = fminf(fminf(u[0][0], u[1][0]), fminf(u[2][0], u[3][0])); \
            float mq1 = fminf(fminf(u[0][1], u[1][1]), fminf(u[2][1], u[3][1])); \
            float mq2 = fminf(fminf(u[0][2], u[1][2]), fminf(u[2][2], u[3][2])); \
            float mq3 = fminf(fminf(u[0][3], u[1][3]), fminf(u[2][3], u[3][3])); \
            float pa = fminf(mq0, DPPX1(mq0));                               \
            float pb = fminf(mq1, DPPX1(mq1));                               \
            float r01 = h0 ? pb : pa;                                        \
            pa = fminf(mq2, DPPX1(mq2));                                     \
            pb = fminf(mq3, DPPX1(mq3));                                     \
            float r23 = h0 ? pb : pa;                                        \
            pa = fminf(r01, DPPX2(r01));                                     \
            pb = fminf(r23, DPPX2(r23));                                     \
            mini4[fi] = h1 ? pb : pa;                                        \
        }                                                                    \
        {                                                                    \
            float pa = fminf(mini4[0], __shfl_xor(mini4[0], 4));             \
            float pb = fminf(mini4[1], __shfl_xor(mini4[1], 4));             \
            float A = h2 ? pb : pa;                                          \
            pa = fminf(mini4[2], __shfl_xor(mini4[2], 4));                   \
            pb = fminf(mini4[3], __shfl_xor(mini4[3], 4));                   \
            float B = h2 ? pb : pa;                                          \
            pa = fminf(A, __shfl_xor(A, 8));                                 \
            pb = fminf(B, __shfl_xor(B, 8));                                 \
            float Mi = h3 ? pb : pa;                                         \
            float dmin = __builtin_amdgcn_sqrtf(fmaxf(Mi, 0.f));             \
            int ii = ibase + ((rf >> 2) << 4) + (kg << 2) + (rf & 3);        \
            atomicMin(&sbm2[p][ii], __float_as_uint(dmin));                  \
        }                                                                    \
        {                                                                    \
            float pa = fminf(minj[0], __shfl_xor(minj[0], 32));              \
            float pb = fminf(minj[1], __shfl_xor(minj[1], 32));              \
            float A = h5 ? pb : pa;                                          \
            pa = fminf(minj[2], __shfl_xor(minj[2], 32));                    \
            pb = fminf(minj[3], __shfl_xor(minj[3], 32));                    \
            float B = h5 ? pb : pa;                                          \
            pa = fminf(A, __shfl_xor(A, 16));                                \
            pb = fminf(B, __shfl_xor(B, 16));                                \
            float Mj = h4 ? pb : pa;                                         \
            float dminj = __builtin_amdgcn_sqrtf(fmaxf(Mj, 0.f));            \
            int fjf = ((lane >> 5) & 1) | (((lane >> 4) & 1) << 1);          \
            atomicMin(&sbm1[p][jbase + (fjf << 4) + rf], __float_as_uint(dminj)); \
        }                                                                    \
    }

    // ---- pair 0 (pair-1 q0/q1 staged before epilogue0 -> overlap) ----
    WAITV2(); BAR(); COMPUTE(0, 0); BAR(); STAGE_B(0, gB0, 2);
    WAITV2(); BAR(); COMPUTE(1, 1); BAR(); STAGE_B(1, gB0, 3);
    WAITV2(); BAR(); COMPUTE(0, 2); BAR(); STAGE_B(0, gB1, 0);
    WAITV2(); BAR(); COMPUTE(1, 3); BAR(); STAGE_B(1, gB1, 1);
    EPILOGUE(0);

    // ---- pair 1 ----
#pragma unroll
    for (int fi = 0; fi < 4; ++fi)
#pragma unroll
        for (int fj = 0; fj < 4; ++fj)
            acc[fi][fj] = (f32x4){0.f, 0.f, 0.f, 0.f};

    WAITV2(); BAR(); COMPUTE(0, 0); BAR(); STAGE_B(0, gB1, 2);
    WAITV2(); BAR(); COMPUTE(1, 1); BAR(); STAGE_B(1, gB1, 3);
    WAITV2(); BAR(); COMPUTE(0, 2); BAR();
    WAITV0(); BAR(); COMPUTE(1, 3);
    EPILOGUE(1);

#undef COMPUTE
#undef STAGE_A
#undef STAGE_B
#undef EPILOGUE
#undef WAITV2
#undef WAITV0
#undef BAR

    __syncthreads();

    // Final reduce: threads 0-127 -> pair 0, 128-255 -> pair 1.
    {
        const int p = tid >> 7;
        const int e = tid & 127;
        const int nn2 = n2v[p];
        float v = 0.f;
        if (n1 > 0 && e < nn2) v += __uint_as_float(sbm1[p][e]);
        if (nn2 > 0 && e < n1) v += __uint_as_float(sbm2[p][e]);
#pragma unroll
        for (int off = 32; off >= 1; off >>= 1) v += __shfl_down(v, off);
        if (lane == 0) swsum[wid] = v;
    }
    __syncthreads();
    if (tid == 0)   out[(b1 << 6) + b2base + 0] = swsum[0] + swsum[1];
    if (tid == 128) out[(b1 << 6) + b2base + 1] = swsum[2] + swsum[3];
}

extern "C" void kernel_launch(void* const* d_in, const int* in_sizes, int n_in,
                              void* d_out, int out_size, void* d_ws, size_t ws_size,
                              hipStream_t stream) {
    const float* v1  = (const float*)d_in[0];
    const int*   sz1 = (const int*)d_in[1];
    const float* v2  = (const float*)d_in[2];
    const int*   sz2 = (const int*)d_in[3];
    float* out = (float*)d_out;
    (void)in_sizes; (void)n_in; (void)out_size; (void)ws_size;

    char* ws = (char*)d_ws;
    ushort_t* v1b = (ushort_t*)ws;                       // 2 MB
    ushort_t* v2b = (ushort_t*)(ws + (2u << 20));        // 2 MB
    float*    x2g = (float*)(ws + (4u << 20));           // 32 KB
    float*    y2g = x2g + 64 * 128;                      // 32 KB

    softhd_pre<<<dim3(1024), dim3(256), 0, stream>>>(v1, v2, v1b, v2b, x2g, y2g);
    softhd_mfma<<<dim3(2048), dim3(256), 0, stream>>>(v1b, v2b, x2g, y2g,
                                                      sz1, sz2, out);
}

// Round 15
// 31.791 us; speedup vs baseline: 1.2413x; 1.0662x over previous
//
#include <hip/hip_runtime.h>
#include <math.h>

// SoftHd via bf16 MFMA. Hybrid operand placement: A panel staged ONCE into
// LDS (the 2x-reused operand), B fragments loaded DIRECTLY global->VGPR from
// the quarter-blocked layout (disjoint per-lane 16B, coalesced 128B segments,
// L1 serves the duplicate wave). K-loop is barrier-free (A read-only after
// prologue; B waits are compiler-managed vmcnt). 2 b2-panels per block.
// out[b1,b2] = sum_{j<sz2} min_{i<sz1} dist[i,j] + sum_{i<sz1} min_{j<sz2} dist[i,j]
// dist via gemm identity on bf16-rounded inputs; sqrt monotone -> mins on
// squared distances, sqrt after reduction; masking folded into +INF operands.
// Quarter-blocked global bf16 layout (pre-kernel):
//   panel byte off(r,c16) = (c16>>2)*8192 + (r>>3)*512 + (c16&3)*128 + (r&7)*16

typedef __attribute__((ext_vector_type(8))) short short8;
typedef __attribute__((ext_vector_type(4))) float f32x4;
typedef unsigned int u32;
typedef unsigned short ushort_t;

static __device__ __forceinline__ ushort_t f32_to_bf16_rne(float f) {
    u32 b = __float_as_uint(f);
    b += 0x7FFFu + ((b >> 16) & 1u);
    return (ushort_t)(b >> 16);
}

// DPP quad_perm folds (VALU pipe): xor1 = 0xB1, xor2 = 0x4E.
#define DPPX1(x) __int_as_float(__builtin_amdgcn_update_dpp( \
    0, __float_as_int(x), 0xB1, 0xF, 0xF, true))
#define DPPX2(x) __int_as_float(__builtin_amdgcn_update_dpp( \
    0, __float_as_int(x), 0x4E, 0xF, 0xF, true))

// ---------------------------------------------------------------------------
// Pre-kernel: f32 -> bf16 into quarter-blocked layout + per-row squared norms
// (fp32 of the ROUNDED values).
// ---------------------------------------------------------------------------
__global__ __launch_bounds__(256) void softhd_pre(
    const float* __restrict__ v1, const float* __restrict__ v2,
    ushort_t* __restrict__ v1b, ushort_t* __restrict__ v2b,
    float* __restrict__ x2g, float* __restrict__ y2g)
{
    int flat = blockIdx.x * 256 + threadIdx.x;
    int c = flat & 15;
    int r = (flat >> 4) & 127;
    int b = (flat >> 11) & 63;
    int t = flat >> 17;

    const float* src = (t ? v2 : v1) + ((size_t)((b << 7) + r) << 7) + c * 8;
    char* dstp = (char*)((t ? v2b : v1b) + ((size_t)b << 14));

    float4 q0 = *(const float4*)(src);
    float4 q1 = *(const float4*)(src + 4);

    ushort_t h[8];
    h[0] = f32_to_bf16_rne(q0.x); h[1] = f32_to_bf16_rne(q0.y);
    h[2] = f32_to_bf16_rne(q0.z); h[3] = f32_to_bf16_rne(q0.w);
    h[4] = f32_to_bf16_rne(q1.x); h[5] = f32_to_bf16_rne(q1.y);
    h[6] = f32_to_bf16_rne(q1.z); h[7] = f32_to_bf16_rne(q1.w);

    float p = 0.f;
#pragma unroll
    for (int k = 0; k < 8; ++k) {
        float fv = __uint_as_float((u32)h[k] << 16);
        p += fv * fv;
    }

    uint4 w;
    w.x = (u32)h[0] | ((u32)h[1] << 16);
    w.y = (u32)h[2] | ((u32)h[3] << 16);
    w.z = (u32)h[4] | ((u32)h[5] << 16);
    w.w = (u32)h[6] | ((u32)h[7] << 16);

    int off = ((c >> 2) << 13) + ((r >> 3) << 9) + ((c & 3) << 7) + ((r & 7) << 4);
    *(uint4*)(dstp + off) = w;

    p += __shfl_xor(p, 1);
    p += __shfl_xor(p, 2);
    p += __shfl_xor(p, 4);
    p += __shfl_xor(p, 8);
    if (c == 0) (t ? y2g : x2g)[(b << 7) + r] = p;
}

// ---------------------------------------------------------------------------
// Main kernel: 2048 blocks = 64 b1 x 32 b2-pairs. 4 waves, 2x2 quadrant split
// per pair (64x64 out per wave). A panel (32 KB) in LDS; B direct to VGPR.
// ---------------------------------------------------------------------------
__global__ __launch_bounds__(256, 3) void softhd_mfma(
    const ushort_t* __restrict__ v1b, const ushort_t* __restrict__ v2b,
    const float* __restrict__ x2g, const float* __restrict__ y2g,
    const int* __restrict__ sz1, const int* __restrict__ sz2,
    float* __restrict__ out)
{
    __shared__ __align__(16) ushort_t sA[4 * 4096];    // full A panel, 32 KB
    __shared__ float sx2[128], sy2[2][128];
    __shared__ u32 sbm1[2][128], sbm2[2][128];
    __shared__ float swsum[4];

    const int tid = threadIdx.x;
    const int lane = tid & 63;
    const int wid = tid >> 6;
    // XCD-bijective swizzle (2048 % 8 == 0).
    const int bid = ((blockIdx.x & 7) << 8) | (blockIdx.x >> 3);
    const int b1 = bid >> 5;
    const int b2base = (bid & 31) << 1;

    const char* gA = (const char*)(v1b + ((size_t)b1 << 14));
    const char* gB0 = (const char*)(v2b + ((size_t)(b2base + 0) << 14));
    const char* gB1 = (const char*)(v2b + ((size_t)(b2base + 1) << 14));

    const int n1 = min(max(sz1[b1], 0), 128);
    int n2v[2];
    n2v[0] = min(max(sz2[b2base + 0], 0), 128);
    n2v[1] = min(max(sz2[b2base + 1], 0), 128);

    // A panel: 32 KB linear copy, 8 x 16B per thread (global_load_lds w=16).
#pragma unroll
    for (int e = 0; e < 8; ++e) {
        int m16 = ((e << 8) + tid) << 4;
        __builtin_amdgcn_global_load_lds(
            (const __attribute__((address_space(1))) u32*)(gA + m16),
            (__attribute__((address_space(3))) u32*)((char*)&sA[0] + m16),
            16, 0, 0);
    }

    if (tid < 128) {
        sx2[tid] = x2g[(b1 << 7) + tid];
    } else {
        sy2[0][tid - 128] = y2g[((b2base + 0) << 7) + (tid - 128)];
        sy2[1][tid - 128] = y2g[((b2base + 1) << 7) + (tid - 128)];
    }
    ((u32*)sbm1)[tid] = 0x7F800000u;        // +inf bits (2x128 slots)
    ((u32*)sbm2)[tid] = 0x7F800000u;
    __syncthreads();                        // A resident + init visible

    const int qr = wid >> 1, qc = wid & 1;
    const int ibase = qr << 6, jbase = qc << 6;
    const int rf = lane & 15, kg = lane >> 4;
    const bool h0 = lane & 1, h1 = lane & 2, h2 = lane & 4, h3 = lane & 8;
    const bool h4 = lane & 16, h5 = lane & 32;

    // A frag elem offsets within an 8 KB quarter: (row>>3)*256 + kg*64 + (row&7)*8
    // B frag BYTE offsets within a quarter block:  (row>>3)*512 + kg*128 + (row&7)*16
    int aoff[4], boffB[4];
#pragma unroll
    for (int f = 0; f < 4; ++f) {
        int ra = ibase + (f << 4) + rf;
        int rb = jbase + (f << 4) + rf;
        aoff[f]  = ((ra >> 3) << 8) + (kg << 6) + ((ra & 7) << 3);
        boffB[f] = ((rb >> 3) << 9) + (kg << 7) + ((rb & 7) << 4);
    }

    f32x4 acc[4][4];
#pragma unroll
    for (int fi = 0; fi < 4; ++fi)
#pragma unroll
        for (int fj = 0; fj < 4; ++fj)
            acc[fi][fj] = (f32x4){0.f, 0.f, 0.f, 0.f};

#define LOADB(B, gB, q)                                                      \
    {                                                                        \
        _Pragma("unroll")                                                    \
        for (int f = 0; f < 4; ++f)                                          \
            B[f] = *(const short8*)((gB) + ((q) << 13) + boffB[f]);          \
    }
#define COMP(B, q)                                                           \
    {                                                                        \
        short8 a[4];                                                         \
        _Pragma("unroll")                                                    \
        for (int f = 0; f < 4; ++f)                                          \
            a[f] = *(const short8*)(&sA[(q) << 12] + aoff[f]);               \
        __builtin_amdgcn_s_setprio(1);                                       \
        _Pragma("unroll")                                                    \
        for (int fi = 0; fi < 4; ++fi)                                       \
            _Pragma("unroll")                                                \
            for (int fj = 0; fj < 4; ++fj)                                   \
                acc[fi][fj] = __builtin_amdgcn_mfma_f32_16x16x32_bf16(       \
                    a[fi], B[fj], acc[fi][fj], 0, 0, 0);                     \
        __builtin_amdgcn_s_setprio(0);                                       \
    }

    const float INF = __builtin_inff();

    // DPP epilogue (R13/R14-verified), pair-indexed sbm/sy2/n2.
#define EPILOGUE(p)                                                          \
    {                                                                        \
        const int nn2 = n2v[p];                                              \
        float yje[4];                                                        \
        _Pragma("unroll")                                                    \
        for (int fj = 0; fj < 4; ++fj) {                                     \
            int j = jbase + (fj << 4) + rf;                                  \
            yje[fj] = (j < nn2) ? sy2[p][j] : INF;                           \
        }                                                                    \
        float minj[4] = {INF, INF, INF, INF};                                \
        float mini4[4];                                                      \
        _Pragma("unroll")                                                    \
        for (int fi = 0; fi < 4; ++fi) {                                     \
            const int i0 = ibase + (fi << 4) + (kg << 2);                    \
            float4 xs = *(const float4*)&sx2[i0];                            \
            float xie[4];                                                    \
            xie[0] = (i0 + 0 < n1) ? xs.x : INF;                             \
            xie[1] = (i0 + 1 < n1) ? xs.y : INF;                             \
            xie[2] = (i0 + 2 < n1) ? xs.z : INF;                             \
            xie[3] = (i0 + 3 < n1) ? xs.w : INF;                             \
            float u[4][4];                                                   \
            _Pragma("unroll")                                                \
            for (int fj = 0; fj < 4; ++fj) {                                 \
                _Pragma("unroll")                                            \
                for (int q = 0; q < 4; ++q)                                  \
                    u[fj][q] = fmaf(acc[fi][fj][q], -2.f, xie[q] + yje[fj]); \
                minj[fj] = fminf(fminf(minj[fj], u[fj][0]), u[fj][1]);       \
                minj[fj] = fminf(fminf(minj[fj], u[fj][2]), u[fj][3]);       \
            }                                                                \
            float mq0 = fminf(fminf(u[0][0], u[1][0]), fminf(u[2][0], u[3][0])); \
            float mq1 = fminf(fminf(u[0][1], u[1][1]), fminf(u[2][1], u[3][1])); \
            float mq2 = fminf(fminf(u[0][2], u[1][2]), fminf(u[2][2], u[3][2])); \
            float mq3 = fminf(fminf(u[0][3], u[1][3]), fminf(u[2][3], u[3][3])); \
            float pa = fminf(mq0, DPPX1(mq0));                               \
            float pb = fminf(mq1, DPPX1(mq1));                               \
            float r01 = h0 ? pb : pa;                                        \
            pa = fminf(mq2, DPPX1(mq2));                                     \
            pb = fminf(mq3, DPPX1(mq3));                                     \
            float r23 = h0 ? pb : pa;                                        \
            pa = fminf(r01, DPPX2(r01));                                     \
            pb = fminf(r23, DPPX2(r23));                                     \
            mini4[fi] = h1 ? pb : pa;                                        \
        }                                                                    \
        {                                                                    \
            float pa = fminf(mini4[0], __shfl_xor(mini4[0], 4));             \
            float pb = fminf(mini4[1], __shfl_xor(mini4[1], 4));             \
            float A = h2 ? pb : pa;                                          \
            pa = fminf(mini4[2], __shfl_xor(mini4[2], 4));                   \
            pb = fminf(mini4[3], __shfl_xor(mini4[3], 4));                   \
            float B = h2 ? pb : pa;                                          \
            pa = fminf(A, __shfl_xor(A, 8));                                 \
            pb = fminf(B, __shfl_xor(B, 8));                                 \
            float Mi = h3 ? pb : pa;                                         \
            float dmin = __builtin_amdgcn_sqrtf(fmaxf(Mi, 0.f));             \
            int ii = ibase + ((rf >> 2) << 4) + (kg << 2) + (rf & 3);        \
            atomicMin(&sbm2[p][ii], __float_as_uint(dmin));                  \
        }                                                                    \
        {                                                                    \
            float pa = fminf(minj[0], __shfl_xor(minj[0], 32));              \
            float pb = fminf(minj[1], __shfl_xor(minj[1], 32));              \
            float A = h5 ? pb : pa;                                          \
            pa = fminf(minj[2], __shfl_xor(minj[2], 32));                    \
            pb = fminf(minj[3], __shfl_xor(minj[3], 32));                    \
            float B = h5 ? pb : pa;                                          \
            pa = fminf(A, __shfl_xor(A, 16));                                \
            pb = fminf(B, __shfl_xor(B, 16));                                \
            float Mj = h4 ? pb : pa;                                         \
            float dminj = __builtin_amdgcn_sqrtf(fmaxf(Mj, 0.f));            \
            int fjf = ((lane >> 5) & 1) | (((lane >> 4) & 1) << 1);          \
            atomicMin(&sbm1[p][jbase + (fjf << 4) + rf], __float_as_uint(dminj)); \
        }                                                                    \
    }

    short8 bfA[4], bfB[4];

    // ---- pair 0 (barrier-free K loop; B waits compiler-managed) ----
    LOADB(bfA, gB0, 0); LOADB(bfB, gB0, 1);
    COMP(bfA, 0); LOADB(bfA, gB0, 2);
    COMP(bfB, 1); LOADB(bfB, gB0, 3);
    COMP(bfA, 2);
    COMP(bfB, 3);
    LOADB(bfA, gB1, 0); LOADB(bfB, gB1, 1);   // pair-1 prefetch under epilogue
    EPILOGUE(0);

    // ---- pair 1 ----
#pragma unroll
    for (int fi = 0; fi < 4; ++fi)
#pragma unroll
        for (int fj = 0; fj < 4; ++fj)
            acc[fi][fj] = (f32x4){0.f, 0.f, 0.f, 0.f};

    COMP(bfA, 0); LOADB(bfA, gB1, 2);
    COMP(bfB, 1); LOADB(bfB, gB1, 3);
    COMP(bfA, 2);
    COMP(bfB, 3);
    EPILOGUE(1);

#undef LOADB
#undef COMP
#undef EPILOGUE

    __syncthreads();                        // atomics visible

    // Final reduce: threads 0-127 -> pair 0, 128-255 -> pair 1.
    {
        const int p = tid >> 7;
        const int e = tid & 127;
        const int nn2 = n2v[p];
        float v = 0.f;
        if (n1 > 0 && e < nn2) v += __uint_as_float(sbm1[p][e]);
        if (nn2 > 0 && e < n1) v += __uint_as_float(sbm2[p][e]);
#pragma unroll
        for (int off = 32; off >= 1; off >>= 1) v += __shfl_down(v, off);
        if (lane == 0) swsum[wid] = v;
    }
    __syncthreads();
    if (tid == 0)   out[(b1 << 6) + b2base + 0] = swsum[0] + swsum[1];
    if (tid == 128) out[(b1 << 6) + b2base + 1] = swsum[2] + swsum[3];
}

extern "C" void kernel_launch(void* const* d_in, const int* in_sizes, int n_in,
                              void* d_out, int out_size, void* d_ws, size_t ws_size,
                              hipStream_t stream) {
    const float* v1  = (const float*)d_in[0];
    const int*   sz1 = (const int*)d_in[1];
    const float* v2  = (const float*)d_in[2];
    const int*   sz2 = (const int*)d_in[3];
    float* out = (float*)d_out;
    (void)in_sizes; (void)n_in; (void)out_size; (void)ws_size;

    char* ws = (char*)d_ws;
    ushort_t* v1b = (ushort_t*)ws;                       // 2 MB
    ushort_t* v2b = (ushort_t*)(ws + (2u << 20));        // 2 MB
    float*    x2g = (float*)(ws + (4u << 20));           // 32 KB
    float*    y2g = x2g + 64 * 128;                      // 32 KB

    softhd_pre<<<dim3(1024), dim3(256), 0, stream>>>(v1, v2, v1b, v2b, x2g, y2g);
    softhd_mfma<<<dim3(2048), dim3(256), 0, stream>>>(v1b, v2b, x2g, y2g,
                                                      sz1, sz2, out);
}

// Round 16
// 29.926 us; speedup vs baseline: 1.3186x; 1.0623x over previous
//
#include <hip/hip_runtime.h>
#include <math.h>

// SoftHd via bf16 MFMA. R15 hybrid (A once->LDS, B direct->VGPR, barrier-free
// K loop, DPP epilogue, 2 pairs/block) + WAVE-LEVEL DEAD-QUADRANT SKIP:
// a wave contributes nothing unless (ibase < n1) && (jbase < n2) — its minj
// operands are +INF (atomicMin no-op) and its mini slots are never summed.
// Expected live work ~56% for sz ~ U[0,128). Branch is wave-uniform.
// out[b1,b2] = sum_{j<sz2} min_{i<sz1} dist[i,j] + sum_{i<sz1} min_{j<sz2} dist[i,j]
// dist via gemm identity on bf16-rounded inputs; sqrt monotone -> mins on
// squared distances, sqrt after reduction; masking folded into +INF operands.
// Quarter-blocked global bf16 layout (pre-kernel):
//   panel byte off(r,c16) = (c16>>2)*8192 + (r>>3)*512 + (c16&3)*128 + (r&7)*16

typedef __attribute__((ext_vector_type(8))) short short8;
typedef __attribute__((ext_vector_type(4))) float f32x4;
typedef unsigned int u32;
typedef unsigned short ushort_t;

static __device__ __forceinline__ ushort_t f32_to_bf16_rne(float f) {
    u32 b = __float_as_uint(f);
    b += 0x7FFFu + ((b >> 16) & 1u);
    return (ushort_t)(b >> 16);
}

// DPP quad_perm folds (VALU pipe): xor1 = 0xB1, xor2 = 0x4E.
#define DPPX1(x) __int_as_float(__builtin_amdgcn_update_dpp( \
    0, __float_as_int(x), 0xB1, 0xF, 0xF, true))
#define DPPX2(x) __int_as_float(__builtin_amdgcn_update_dpp( \
    0, __float_as_int(x), 0x4E, 0xF, 0xF, true))

// ---------------------------------------------------------------------------
// Pre-kernel: f32 -> bf16 into quarter-blocked layout + per-row squared norms
// (fp32 of the ROUNDED values).
// ---------------------------------------------------------------------------
__global__ __launch_bounds__(256) void softhd_pre(
    const float* __restrict__ v1, const float* __restrict__ v2,
    ushort_t* __restrict__ v1b, ushort_t* __restrict__ v2b,
    float* __restrict__ x2g, float* __restrict__ y2g)
{
    int flat = blockIdx.x * 256 + threadIdx.x;
    int c = flat & 15;
    int r = (flat >> 4) & 127;
    int b = (flat >> 11) & 63;
    int t = flat >> 17;

    const float* src = (t ? v2 : v1) + ((size_t)((b << 7) + r) << 7) + c * 8;
    char* dstp = (char*)((t ? v2b : v1b) + ((size_t)b << 14));

    float4 q0 = *(const float4*)(src);
    float4 q1 = *(const float4*)(src + 4);

    ushort_t h[8];
    h[0] = f32_to_bf16_rne(q0.x); h[1] = f32_to_bf16_rne(q0.y);
    h[2] = f32_to_bf16_rne(q0.z); h[3] = f32_to_bf16_rne(q0.w);
    h[4] = f32_to_bf16_rne(q1.x); h[5] = f32_to_bf16_rne(q1.y);
    h[6] = f32_to_bf16_rne(q1.z); h[7] = f32_to_bf16_rne(q1.w);

    float p = 0.f;
#pragma unroll
    for (int k = 0; k < 8; ++k) {
        float fv = __uint_as_float((u32)h[k] << 16);
        p += fv * fv;
    }

    uint4 w;
    w.x = (u32)h[0] | ((u32)h[1] << 16);
    w.y = (u32)h[2] | ((u32)h[3] << 16);
    w.z = (u32)h[4] | ((u32)h[5] << 16);
    w.w = (u32)h[6] | ((u32)h[7] << 16);

    int off = ((c >> 2) << 13) + ((r >> 3) << 9) + ((c & 3) << 7) + ((r & 7) << 4);
    *(uint4*)(dstp + off) = w;

    p += __shfl_xor(p, 1);
    p += __shfl_xor(p, 2);
    p += __shfl_xor(p, 4);
    p += __shfl_xor(p, 8);
    if (c == 0) (t ? y2g : x2g)[(b << 7) + r] = p;
}

// ---------------------------------------------------------------------------
// Main kernel: 2048 blocks = 64 b1 x 32 b2-pairs. 4 waves, 2x2 quadrant split
// per pair (64x64 out per wave). A panel (32 KB) in LDS; B direct to VGPR.
// ---------------------------------------------------------------------------
__global__ __launch_bounds__(256, 3) void softhd_mfma(
    const ushort_t* __restrict__ v1b, const ushort_t* __restrict__ v2b,
    const float* __restrict__ x2g, const float* __restrict__ y2g,
    const int* __restrict__ sz1, const int* __restrict__ sz2,
    float* __restrict__ out)
{
    __shared__ __align__(16) ushort_t sA[4 * 4096];    // full A panel, 32 KB
    __shared__ float sx2[128], sy2[2][128];
    __shared__ u32 sbm1[2][128], sbm2[2][128];
    __shared__ float swsum[4];

    const int tid = threadIdx.x;
    const int lane = tid & 63;
    const int wid = tid >> 6;
    // XCD-bijective swizzle (2048 % 8 == 0).
    const int bid = ((blockIdx.x & 7) << 8) | (blockIdx.x >> 3);
    const int b1 = bid >> 5;
    const int b2base = (bid & 31) << 1;

    const char* gA = (const char*)(v1b + ((size_t)b1 << 14));
    const char* gB0 = (const char*)(v2b + ((size_t)(b2base + 0) << 14));
    const char* gB1 = (const char*)(v2b + ((size_t)(b2base + 1) << 14));

    const int n1 = min(max(sz1[b1], 0), 128);
    int n2v[2];
    n2v[0] = min(max(sz2[b2base + 0], 0), 128);
    n2v[1] = min(max(sz2[b2base + 1], 0), 128);

    // A panel: 32 KB linear copy, 8 x 16B per thread. Odd e chunks are rows
    // 64-127 (second 4 KB of each 8 KB quarter) — only needed if n1 > 64.
    {
        const bool hiA = n1 > 64;
#pragma unroll
        for (int e = 0; e < 8; ++e) {
            if ((e & 1) == 0 || hiA) {
                int m16 = ((e << 8) + tid) << 4;
                __builtin_amdgcn_global_load_lds(
                    (const __attribute__((address_space(1))) u32*)(gA + m16),
                    (__attribute__((address_space(3))) u32*)((char*)&sA[0] + m16),
                    16, 0, 0);
            }
        }
    }

    if (tid < 128) {
        sx2[tid] = x2g[(b1 << 7) + tid];
    } else {
        sy2[0][tid - 128] = y2g[((b2base + 0) << 7) + (tid - 128)];
        sy2[1][tid - 128] = y2g[((b2base + 1) << 7) + (tid - 128)];
    }
    ((u32*)sbm1)[tid] = 0x7F800000u;        // +inf bits (2x128 slots)
    ((u32*)sbm2)[tid] = 0x7F800000u;
    __syncthreads();                        // A resident + init visible

    const int qr = wid >> 1, qc = wid & 1;
    const int ibase = qr << 6, jbase = qc << 6;
    const int rf = lane & 15, kg = lane >> 4;
    const bool h0 = lane & 1, h1 = lane & 2, h2 = lane & 4, h3 = lane & 8;
    const bool h4 = lane & 16, h5 = lane & 32;

    // Dead-quadrant skip (wave-uniform): a wave with all i >= n1 or all
    // j >= n2 contributes only +INF atomicMins / never-read slots.
    const bool act0 = (ibase < n1) && (jbase < n2v[0]);
    const bool act1 = (ibase < n1) && (jbase < n2v[1]);

    // A frag elem offsets within an 8 KB quarter: (row>>3)*256 + kg*64 + (row&7)*8
    // B frag BYTE offsets within a quarter block:  (row>>3)*512 + kg*128 + (row&7)*16
    int aoff[4], boffB[4];
#pragma unroll
    for (int f = 0; f < 4; ++f) {
        int ra = ibase + (f << 4) + rf;
        int rb = jbase + (f << 4) + rf;
        aoff[f]  = ((ra >> 3) << 8) + (kg << 6) + ((ra & 7) << 3);
        boffB[f] = ((rb >> 3) << 9) + (kg << 7) + ((rb & 7) << 4);
    }

    f32x4 acc[4][4];
#pragma unroll
    for (int fi = 0; fi < 4; ++fi)
#pragma unroll
        for (int fj = 0; fj < 4; ++fj)
            acc[fi][fj] = (f32x4){0.f, 0.f, 0.f, 0.f};

#define LOADB(B, gB, q)                                                      \
    {                                                                        \
        _Pragma("unroll")                                                    \
        for (int f = 0; f < 4; ++f)                                          \
            B[f] = *(const short8*)((gB) + ((q) << 13) + boffB[f]);          \
    }
#define COMP(B, q)                                                           \
    {                                                                        \
        short8 a[4];                                                         \
        _Pragma("unroll")                                                    \
        for (int f = 0; f < 4; ++f)                                          \
            a[f] = *(const short8*)(&sA[(q) << 12] + aoff[f]);               \
        __builtin_amdgcn_s_setprio(1);                                       \
        _Pragma("unroll")                                                    \
        for (int fi = 0; fi < 4; ++fi)                                       \
            _Pragma("unroll")                                                \
            for (int fj = 0; fj < 4; ++fj)                                   \
                acc[fi][fj] = __builtin_amdgcn_mfma_f32_16x16x32_bf16(       \
                    a[fi], B[fj], acc[fi][fj], 0, 0, 0);                     \
        __builtin_amdgcn_s_setprio(0);                                       \
    }

    const float INF = __builtin_inff();

    // DPP epilogue (R13/R14/R15-verified), pair-indexed sbm/sy2/n2.
#define EPILOGUE(p)                                                          \
    {                                                                        \
        const int nn2 = n2v[p];                                              \
        float yje[4];                                                        \
        _Pragma("unroll")                                                    \
        for (int fj = 0; fj < 4; ++fj) {                                     \
            int j = jbase + (fj << 4) + rf;                                  \
            yje[fj] = (j < nn2) ? sy2[p][j] : INF;                           \
        }                                                                    \
        float minj[4] = {INF, INF, INF, INF};                                \
        float mini4[4];                                                      \
        _Pragma("unroll")                                                    \
        for (int fi = 0; fi < 4; ++fi) {                                     \
            const int i0 = ibase + (fi << 4) + (kg << 2);                    \
            float4 xs = *(const float4*)&sx2[i0];                            \
            float xie[4];                                                    \
            xie[0] = (i0 + 0 < n1) ? xs.x : INF;                             \
            xie[1] = (i0 + 1 < n1) ? xs.y : INF;                             \
            xie[2] = (i0 + 2 < n1) ? xs.z : INF;                             \
            xie[3] = (i0 + 3 < n1) ? xs.w : INF;                             \
            float u[4][4];                                                   \
            _Pragma("unroll")                                                \
            for (int fj = 0; fj < 4; ++fj) {                                 \
                _Pragma("unroll")                                            \
                for (int q = 0; q < 4; ++q)                                  \
                    u[fj][q] = fmaf(acc[fi][fj][q], -2.f, xie[q] + yje[fj]); \
                minj[fj] = fminf(fminf(minj[fj], u[fj][0]), u[fj][1]);       \
                minj[fj] = fminf(fminf(minj[fj], u[fj][2]), u[fj][3]);       \
            }                                                                \
            float mq0 = fminf(fminf(u[0][0], u[1][0]), fminf(u[2][0], u[3][0])); \
            float mq1 = fminf(fminf(u[0][1], u[1][1]), fminf(u[2][1], u[3][1])); \
            float mq2 = fminf(fminf(u[0][2], u[1][2]), fminf(u[2][2], u[3][2])); \
            float mq3 = fminf(fminf(u[0][3], u[1][3]), fminf(u[2][3], u[3][3])); \
            float pa = fminf(mq0, DPPX1(mq0));                               \
            float pb = fminf(mq1, DPPX1(mq1));                               \
            float r01 = h0 ? pb : pa;                                        \
            pa = fminf(mq2, DPPX1(mq2));                                     \
            pb = fminf(mq3, DPPX1(mq3));                                     \
            float r23 = h0 ? pb : pa;                                        \
            pa = fminf(r01, DPPX2(r01));                                     \
            pb = fminf(r23, DPPX2(r23));                                     \
            mini4[fi] = h1 ? pb : pa;                                        \
        }                                                                    \
        {                                                                    \
            float pa = fminf(mini4[0], __shfl_xor(mini4[0], 4));             \
            float pb = fminf(mini4[1], __shfl_xor(mini4[1], 4));             \
            float A = h2 ? pb : pa;                                          \
            pa = fminf(mini4[2], __shfl_xor(mini4[2], 4));                   \
            pb = fminf(mini4[3], __shfl_xor(mini4[3], 4));                   \
            float B = h2 ? pb : pa;                                          \
            pa = fminf(A, __shfl_xor(A, 8));                                 \
            pb = fminf(B, __shfl_xor(B, 8));                                 \
            float Mi = h3 ? pb : pa;                                         \
            float dmin = __builtin_amdgcn_sqrtf(fmaxf(Mi, 0.f));             \
            int ii = ibase + ((rf >> 2) << 4) + (kg << 2) + (rf & 3);        \
            atomicMin(&sbm2[p][ii], __float_as_uint(dmin));                  \
        }                                                                    \
        {                                                                    \
            float pa = fminf(minj[0], __shfl_xor(minj[0], 32));              \
            float pb = fminf(minj[1], __shfl_xor(minj[1], 32));              \
            float A = h5 ? pb : pa;                                          \
            pa = fminf(minj[2], __shfl_xor(minj[2], 32));                    \
            pb = fminf(minj[3], __shfl_xor(minj[3], 32));                    \
            float B = h5 ? pb : pa;                                          \
            pa = fminf(A, __shfl_xor(A, 16));                                \
            pb = fminf(B, __shfl_xor(B, 16));                                \
            float Mj = h4 ? pb : pa;                                         \
            float dminj = __builtin_amdgcn_sqrtf(fmaxf(Mj, 0.f));            \
            int fjf = ((lane >> 5) & 1) | (((lane >> 4) & 1) << 1);          \
            atomicMin(&sbm1[p][jbase + (fjf << 4) + rf], __float_as_uint(dminj)); \
        }                                                                    \
    }

    short8 bfA[4], bfB[4];

    // ---- pair 0 (only if this wave's quadrant is live) ----
    if (act0) {
        LOADB(bfA, gB0, 0); LOADB(bfB, gB0, 1);
        COMP(bfA, 0); LOADB(bfA, gB0, 2);
        COMP(bfB, 1); LOADB(bfB, gB0, 3);
        COMP(bfA, 2);
        COMP(bfB, 3);
        if (act1) { LOADB(bfA, gB1, 0); LOADB(bfB, gB1, 1); }  // prefetch
        EPILOGUE(0);
    }

    // ---- pair 1 ----
    if (act1) {
#pragma unroll
        for (int fi = 0; fi < 4; ++fi)
#pragma unroll
            for (int fj = 0; fj < 4; ++fj)
                acc[fi][fj] = (f32x4){0.f, 0.f, 0.f, 0.f};
        if (!act0) { LOADB(bfA, gB1, 0); LOADB(bfB, gB1, 1); }
        COMP(bfA, 0); LOADB(bfA, gB1, 2);
        COMP(bfB, 1); LOADB(bfB, gB1, 3);
        COMP(bfA, 2);
        COMP(bfB, 3);
        EPILOGUE(1);
    }

#undef LOADB
#undef COMP
#undef EPILOGUE

    __syncthreads();                        // atomics visible

    // Final reduce: threads 0-127 -> pair 0, 128-255 -> pair 1.
    {
        const int p = tid >> 7;
        const int e = tid & 127;
        const int nn2 = n2v[p];
        float v = 0.f;
        if (n1 > 0 && e < nn2) v += __uint_as_float(sbm1[p][e]);
        if (nn2 > 0 && e < n1) v += __uint_as_float(sbm2[p][e]);
#pragma unroll
        for (int off = 32; off >= 1; off >>= 1) v += __shfl_down(v, off);
        if (lane == 0) swsum[wid] = v;
    }
    __syncthreads();
    if (tid == 0)   out[(b1 << 6) + b2base + 0] = swsum[0] + swsum[1];
    if (tid == 128) out[(b1 << 6) + b2base + 1] = swsum[2] + swsum[3];
}

extern "C" void kernel_launch(void* const* d_in, const int* in_sizes, int n_in,
                              void* d_out, int out_size, void* d_ws, size_t ws_size,
                              hipStream_t stream) {
    const float* v1  = (const float*)d_in[0];
    const int*   sz1 = (const int*)d_in[1];
    const float* v2  = (const float*)d_in[2];
    const int*   sz2 = (const int*)d_in[3];
    float* out = (float*)d_out;
    (void)in_sizes; (void)n_in; (void)out_size; (void)ws_size;

    char* ws = (char*)d_ws;
    ushort_t* v1b = (ushort_t*)ws;                       // 2 MB
    ushort_t* v2b = (ushort_t*)(ws + (2u << 20));        // 2 MB
    float*    x2g = (float*)(ws + (4u << 20));           // 32 KB
    float*    y2g = x2g + 64 * 128;                      // 32 KB

    softhd_pre<<<dim3(1024), dim3(256), 0, stream>>>(v1, v2, v1b, v2b, x2g, y2g);
    softhd_mfma<<<dim3(2048), dim3(256), 0, stream>>>(v1b, v2b, x2g, y2g,
                                                      sz1, sz2, out);
}